// Round 4
// baseline (341.415 us; speedup 1.0000x reference)
//
#include <hip/hip_runtime.h>

#define TLEN   500000
#define NITER  100
#define DHALF  10                 // band half-width; weights ~0.135*(1.1)^d/d!
#define NOFF   (2*DHALF+1)        // 21 offsets
#define WQOFF  224                // weights start here in d_ws (floats)
#define STRIP  20                 // edge strip width
#define EWIN   64                 // edge window (one wave)
#define CT     256                // conv threads
#define CCPT   2                  // conv cols per thread
#define CCOLS  (CT*CCPT)          // 512
#define CWIN   (CCOLS + 2*DHALF)  // 532
#define NCONV  ((TLEN - 2*STRIP + CCOLS - 1) / CCOLS)   // 977

// ============ K1: parallel double-precision operator construction ============
// Writes 224 floats to ws: [0..63] CmT, [64..127] PT, [128..191] FuT, [192..223] GT
// (all transposed [k][i]).
__global__ __launch_bounds__(256) void setup_mats(
    const float* __restrict__ F, const float* __restrict__ H,
    const float* __restrict__ Q, const float* __restrict__ R,
    const float* __restrict__ gam, float* __restrict__ mats)
{
  __shared__ double dQaug[8][16];
  __shared__ double dRaug[4][8];
  __shared__ double dFtQi[64], dHtRi[32], dA1[64], dB2[64], dMx[64], dMp[64];
  const int tid = threadIdx.x;

  if (tid < 128) {                 // Q augmented [8][16]
    int r = tid >> 4, c = tid & 15;
    dQaug[r][c] = (c < 8) ? (double)Q[r*8 + c] : ((c - 8 == r) ? 1.0 : 0.0);
  } else if (tid < 160) {          // R augmented [4][8]
    int t = tid - 128, r = t >> 3, c = t & 7;
    dRaug[r][c] = (c < 4) ? (double)R[r*4 + c] : ((c - 4 == r) ? 1.0 : 0.0);
  }
  __syncthreads();
  for (int col = 0; col < 8; ++col) {
    double pq = 0, fq = 0, oq = 0, vq = 0, pr = 0, fr = 0, orr = 0, vr = 0;
    const bool doQ = tid < 128;
    const bool doR = (tid >= 128 && tid < 160 && col < 4);
    int rq = 0, cq = 0, rr = 0, cr = 0;
    if (doQ) {
      rq = tid >> 4; cq = tid & 15;
      pq = dQaug[col][col]; vq = dQaug[col][cq]; fq = dQaug[rq][col]; oq = dQaug[rq][cq];
    }
    if (doR) {
      int t = tid - 128; rr = t >> 3; cr = t & 7;
      pr = dRaug[col][col]; vr = dRaug[col][cr]; fr = dRaug[rr][col]; orr = dRaug[rr][cr];
    }
    __syncthreads();
    if (doQ) dQaug[rq][cq] = (rq == col) ? vq / pq : oq - fq * vq / pq;
    if (doR) dRaug[rr][cr] = (rr == col) ? vr / pr : orr - fr * vr / pr;
    __syncthreads();
  }
  if (tid < 64) {
    int i = tid >> 3, j = tid & 7;
    double s = 0.0;
    for (int k = 0; k < 8; ++k) s += (double)F[k*8 + i] * dQaug[k][j + 8];
    dFtQi[i*8 + j] = s;
  } else if (tid < 96) {
    int t = tid - 64, i = t >> 2, j = t & 3;
    double s = 0.0;
    for (int k = 0; k < 4; ++k) s += (double)H[k*8 + i] * dRaug[k][j + 4];
    dHtRi[i*4 + j] = s;
  } else if (tid < 160) {
    int t = tid - 96, i = t >> 3, j = t & 7;
    dA1[i*8 + j] = (j == 0) ? 0.0 : -dQaug[i][j + 8];
  }
  __syncthreads();
  if (tid < 64) {
    int i = tid >> 3, j = tid & 7;
    dB2[i*8 + j] = (j == 7) ? 0.0 : dFtQi[i*8 + j];
  } else if (tid < 128) {
    int t = tid - 64, i = t >> 3, j = t & 7;
    double s = 0.0;
    for (int k = 0; k < 8; ++k) s -= dA1[i*8 + k] * (double)F[k*8 + j];
    dMp[i*8 + j] = s;
  }
  __syncthreads();
  if (tid < 64) {
    int i = tid >> 3, j = tid & 7;
    double s = dA1[i*8 + j];
    for (int k = 0; k < 8; ++k) s -= dB2[i*8 + k] * (double)F[k*8 + j];
    for (int k = 0; k < 4; ++k) s -= dHtRi[i*4 + k] * (double)H[k*8 + j];
    dMx[i*8 + j] = s;
  }
  __syncthreads();
  {
    double g = (double)gam[0];
    if (tid < 64) {
      int k = tid >> 3, i = tid & 7;
      mats[       k*8 + i] = (float)(((i == k) ? 1.0 : 0.0) + g * dMx[i*8 + k]);
      mats[ 64 +  k*8 + i] = (float)(g * dMp[i*8 + k]);
      mats[128 +  k*8 + i] = (float)(g * dB2[i*8 + k]);
    } else if (tid < 96) {
      int t = tid - 64, k = t >> 3, i = t & 7;
      mats[192 + k*8 + i] = (float)(g * dHtRi[i*4 + k]);
    }
  }
}

// ============ K2: band weights (blocks 0-5) + edge strips (blocks 6,7) ============
// One wave per block. State in VGPRs, neighbor exchange via __shfl, coefficients
// via uniform (scalar) loads from global. No LDS, no barriers.
__global__ __launch_bounds__(64) void band_and_edges(
    const float* __restrict__ xs, const float* __restrict__ ys,
    const float* __restrict__ mats,      // ws[0..224)
    float* __restrict__ wout,            // ws + WQOFF
    float* __restrict__ out)
{
  const int lane = threadIdx.x;
  const int b    = blockIdx.x;

  if (b < 6) {
    // ---- weight recurrence: W'_s = Cm*W_s + P*W_{s+1} + Fu*W_{s-1} ----
    // lane -> (sub, s): sub = lane/23 (columns 2b+sub), s = lane%23 (slot; 0,22 guards)
    const int sub = lane / 23;
    const int s   = lane % 23;
    const int c   = 2*b + sub;
    const bool act   = (sub < 2);
    const bool guard = (s == 0) || (s == 22) || !act;
    float x[8];
    #pragma unroll
    for (int r = 0; r < 8; ++r) x[r] = 0.0f;
    if (act && c < 8 && s == DHALF + 1) x[c] = 1.0f;   // W_0 = I, column c
    // per-iteration injection for y-columns (V_0 += G each step)
    float seed[8];
    {
      const int gk = (c >= 8 && c < 12) ? (c - 8) : 0;
      const bool inj = act && (c >= 8) && (c < 12) && (s == DHALF + 1);
      #pragma unroll
      for (int i = 0; i < 8; ++i) seed[i] = inj ? mats[192 + gk*8 + i] : 0.0f;
    }
    const int sl = (lane == 0)  ? 0  : lane - 1;
    const int sr = (lane >= 63) ? 63 : lane + 1;
    #pragma unroll 1
    for (int it = 0; it < NITER; ++it) {
      float xl[8], xr[8];
      #pragma unroll
      for (int r = 0; r < 8; ++r) { xl[r] = __shfl(x[r], sl); xr[r] = __shfl(x[r], sr); }
      float nx[8];
      #pragma unroll
      for (int i = 0; i < 8; ++i) nx[i] = seed[i];
      #pragma unroll
      for (int k = 0; k < 8; ++k) {
        #pragma unroll
        for (int i = 0; i < 8; ++i) {
          nx[i] = fmaf(mats[       k*8 + i], x[k],  nx[i]);   // Cm
          nx[i] = fmaf(mats[ 64 +  k*8 + i], xr[k], nx[i]);   // P  * W_{s+1}
          if (k < 7)
            nx[i] = fmaf(mats[128 + k*8 + i], xl[k], nx[i]);  // Fu * W_{s-1} (col7 zero)
        }
      }
      #pragma unroll
      for (int r = 0; r < 8; ++r) x[r] = guard ? 0.0f : nx[r];
    }
    if (act && s >= 1 && s <= 21) {
      #pragma unroll
      for (int i = 0; i < 8; ++i) wout[((s - 1)*12 + c)*8 + i] = x[i];
    }
    return;
  }

  // ---- edge strips: exact state iteration on 64 columns, halo via shuffles ----
  const bool left = (b == 6);
  const int col = left ? lane : (TLEN - EWIN + lane);
  float x[8], gy[8];
  #pragma unroll
  for (int r = 0; r < 8; ++r) x[r] = xs[r*TLEN + col];
  {
    float yv[4];
    #pragma unroll
    for (int r = 0; r < 4; ++r) yv[r] = ys[r*TLEN + col];
    #pragma unroll
    for (int i = 0; i < 8; ++i) {
      float a =      mats[192 +      i] * yv[0];
      a = fmaf(mats[192 +  8 + i], yv[1], a);
      a = fmaf(mats[192 + 16 + i], yv[2], a);
      a = fmaf(mats[192 + 24 + i], yv[3], a);
      gy[i] = a;
    }
  }
  const int sl = (lane > 0)  ? lane - 1 : 0;    // clamp: col 0 replicates (x_past)
  const int sr = (lane < 63) ? lane + 1 : 63;   // clamp: col T-1 replicates (x_fut)
  #pragma unroll 1
  for (int it = 0; it < NITER; ++it) {
    float xl[8], xr[8];
    #pragma unroll
    for (int r = 0; r < 8; ++r) { xl[r] = __shfl(x[r], sl); xr[r] = __shfl(x[r], sr); }
    float nx[8];
    #pragma unroll
    for (int i = 0; i < 8; ++i) nx[i] = gy[i];
    #pragma unroll
    for (int k = 0; k < 8; ++k) {
      #pragma unroll
      for (int i = 0; i < 8; ++i) {
        nx[i] = fmaf(mats[       k*8 + i], x[k],  nx[i]);     // Cm
        nx[i] = fmaf(mats[ 64 +  k*8 + i], xl[k], nx[i]);     // P  * x_{t-1}
        if (k < 7)
          nx[i] = fmaf(mats[128 + k*8 + i], xr[k], nx[i]);    // Fu * x_{t+1}
      }
    }
    #pragma unroll
    for (int r = 0; r < 8; ++r) x[r] = nx[r];
  }
  if (left) {
    if (lane < STRIP)
      #pragma unroll
      for (int r = 0; r < 8; ++r) out[r*TLEN + col] = x[r];
  } else {
    if (lane >= EWIN - STRIP)
      #pragma unroll
      for (int r = 0; r < 8; ++r) out[r*TLEN + col] = x[r];
  }
}

// ============ K3: interior band convolution ============
__global__ __launch_bounds__(CT) void kgm_conv(
    const float* __restrict__ xs, const float* __restrict__ ys,
    const float* __restrict__ wq, float* __restrict__ out)
{
  __shared__ __align__(16) float buf[CWIN * 12];   // [col][12], 48B stride
  const int tid = threadIdx.x;
  const int c0  = STRIP + blockIdx.x * CCOLS;
  for (int k = 0; k < 12; ++k) {
    const float* src = (k < 8) ? (xs + k*TLEN) : (ys + (k-8)*TLEN);
    for (int c = tid; c < CWIN; c += CT) {
      int g = c0 - DHALF + c;
      if (g > TLEN - 1) g = TLEN - 1;
      buf[c*12 + k] = src[g];
    }
  }
  __syncthreads();

  const float* base = buf + (2*tid)*12;
  float a0[8] = {0,0,0,0,0,0,0,0};
  float a1[8] = {0,0,0,0,0,0,0,0};
  float A[12], B[12];
  {
    float4 u = *(const float4*)(base);
    float4 v = *(const float4*)(base + 4);
    float4 w = *(const float4*)(base + 8);
    A[0]=u.x;A[1]=u.y;A[2]=u.z;A[3]=u.w;A[4]=v.x;A[5]=v.y;A[6]=v.z;A[7]=v.w;A[8]=w.x;A[9]=w.y;A[10]=w.z;A[11]=w.w;
  }
  #define LOADCOL(dst, j1) { \
    const float* p_ = base + (j1)*12; \
    float4 u = *(const float4*)(p_); \
    float4 v = *(const float4*)(p_ + 4); \
    float4 w = *(const float4*)(p_ + 8); \
    dst[0]=u.x;dst[1]=u.y;dst[2]=u.z;dst[3]=u.w;dst[4]=v.x;dst[5]=v.y;dst[6]=v.z;dst[7]=v.w;dst[8]=w.x;dst[9]=w.y;dst[10]=w.z;dst[11]=w.w; }
  #define FMABLK(wd, c0v, c1v) { \
    _Pragma("unroll") \
    for (int k = 0; k < 12; ++k) { \
      _Pragma("unroll") \
      for (int i = 0; i < 8; ++i) { \
        float wk = (wd)[k*8 + i]; \
        a0[i] = fmaf(wk, (c0v)[k], a0[i]); \
        a1[i] = fmaf(wk, (c1v)[k], a1[i]); \
      } } }

  #pragma unroll 1
  for (int j = 0; j + 2 <= NOFF; j += 2) {
    LOADCOL(B, j + 1);
    FMABLK(wq + j*96, A, B);
    LOADCOL(A, j + 2);
    FMABLK(wq + (j+1)*96, B, A);
  }
  LOADCOL(B, NOFF);
  FMABLK(wq + (NOFF-1)*96, A, B);
  #undef LOADCOL
  #undef FMABLK

  const int col = c0 + 2*tid;
  if (col < TLEN - STRIP) {
    #pragma unroll
    for (int i = 0; i < 8; ++i) out[i*TLEN + col] = a0[i];
  }
  if (col + 1 < TLEN - STRIP) {
    #pragma unroll
    for (int i = 0; i < 8; ++i) out[i*TLEN + col + 1] = a1[i];
  }
}

extern "C" void kernel_launch(void* const* d_in, const int* in_sizes, int n_in,
                              void* d_out, int out_size, void* d_ws, size_t ws_size,
                              hipStream_t stream)
{
  (void)in_sizes; (void)n_in; (void)out_size; (void)ws_size;
  const float* xs = (const float*)d_in[0];
  const float* ys = (const float*)d_in[1];
  const float* F  = (const float*)d_in[2];
  const float* H  = (const float*)d_in[3];
  const float* Q  = (const float*)d_in[4];
  const float* R  = (const float*)d_in[5];
  const float* ga = (const float*)d_in[6];
  float* ws  = (float*)d_ws;     // [0,224): operator mats; [224, 224+2016): band weights
  float* out = (float*)d_out;
  setup_mats<<<1, 256, 0, stream>>>(F, H, Q, R, ga, ws);
  band_and_edges<<<8, 64, 0, stream>>>(xs, ys, ws, ws + WQOFF, out);
  kgm_conv<<<NCONV, CT, 0, stream>>>(xs, ys, ws + WQOFF, out);
}

// Round 5
// 142.825 us; speedup vs baseline: 2.3904x; 2.3904x over previous
//
#include <hip/hip_runtime.h>

#define TLEN   500000
#define NITER  100
#define DHALF  10                 // band half-width; weights ~0.135*(1.1)^d/d!
#define NOFF   (2*DHALF+1)        // 21 offsets
#define STRIP  20                 // edge strip width
#define EWIN   64                 // edge window (one wave)
#define CT     256                // conv threads
#define CCPT   2                  // conv cols per thread
#define CCOLS  (CT*CCPT)          // 512
#define CWIN   (CCOLS + 2*DHALF)  // 532
#define NCONV  ((TLEN - 2*STRIP + CCOLS - 1) / CCOLS)   // 977

// ============ K1: band weights (blocks 0-5) + edge strips (blocks 6,7) ============
// One wave per block. Every block first builds the 224 operator coefficients
// (double-precision Gauss-Jordan in LDS, redundant per block), then hoists all
// hot-loop coefficients into per-lane VGPR arrays. The 100-iteration loop is
// pure VALU FMA + 16 shuffles; no memory traffic.
__global__ __launch_bounds__(64, 1) void band_and_edges(
    const float* __restrict__ xs, const float* __restrict__ ys,
    const float* __restrict__ F, const float* __restrict__ H,
    const float* __restrict__ Q, const float* __restrict__ R,
    const float* __restrict__ gam,
    float* __restrict__ wout,            // d_ws: 21*12*8 floats
    float* __restrict__ out)
{
  __shared__ double dQaug[8][16];
  __shared__ double dRaug[4][8];
  __shared__ double dFtQi[64], dHtRi[32], dA1[64], dB2[64];
  __shared__ float fmats[224];

  const int lane = threadIdx.x;
  const int b    = blockIdx.x;
  const int r8 = lane >> 3, c8 = lane & 7;

  // ---- augmented systems ----
  dQaug[r8][c8]     = (double)Q[r8*8 + c8];
  dQaug[r8][c8 + 8] = (c8 == r8) ? 1.0 : 0.0;
  if (lane < 32) {
    int rr = lane >> 3, cr = lane & 7;
    dRaug[rr][cr] = (cr < 4) ? (double)R[rr*4 + cr] : ((cr - 4 == rr) ? 1.0 : 0.0);
  }
  __syncthreads();
  // ---- Gauss-Jordan (no pivoting: Q,R SPD) ----
  for (int col = 0; col < 8; ++col) {
    double piv = dQaug[col][col];
    double fq  = dQaug[r8][col];
    double p1  = dQaug[col][c8], p2 = dQaug[col][c8 + 8];
    double m1  = dQaug[r8][c8],  m2 = dQaug[r8][c8 + 8];
    double rpiv = 1.0, frr = 0.0, pr = 0.0, mr = 0.0;
    const bool doR = (lane < 32) && (col < 4);
    if (doR) {
      int rr = lane >> 3, cr = lane & 7;
      rpiv = dRaug[col][col]; frr = dRaug[rr][col];
      pr = dRaug[col][cr];    mr = dRaug[rr][cr];
    }
    __syncthreads();
    dQaug[r8][c8]     = (r8 == col) ? m1 / piv : m1 - fq * (p1 / piv);
    dQaug[r8][c8 + 8] = (r8 == col) ? m2 / piv : m2 - fq * (p2 / piv);
    if (doR) {
      int rr = lane >> 3, cr = lane & 7;
      dRaug[rr][cr] = (rr == col) ? mr / rpiv : mr - frr * (pr / rpiv);
    }
    __syncthreads();
  }
  // ---- operator products ----
  {
    double s = 0.0;
    #pragma unroll
    for (int k = 0; k < 8; ++k) s += (double)F[k*8 + r8] * dQaug[k][c8 + 8];
    dFtQi[r8*8 + c8] = s;
  }
  if (lane < 32) {
    int i = lane >> 2, j = lane & 3;
    double s = 0.0;
    #pragma unroll
    for (int k = 0; k < 4; ++k) s += (double)H[k*8 + i] * dRaug[k][j + 4];
    dHtRi[i*4 + j] = s;
  }
  dA1[r8*8 + c8] = (c8 == 0) ? 0.0 : -dQaug[r8][c8 + 8];
  __syncthreads();
  dB2[r8*8 + c8] = (c8 == 7) ? 0.0 : dFtQi[r8*8 + c8];
  __syncthreads();
  {
    const double g = (double)gam[0];
    double sp = 0.0;
    #pragma unroll
    for (int k = 0; k < 8; ++k) sp -= dA1[r8*8 + k] * (double)F[k*8 + c8];
    double t = dA1[r8*8 + c8];
    #pragma unroll
    for (int k = 0; k < 8; ++k) t -= dB2[r8*8 + k] * (double)F[k*8 + c8];
    #pragma unroll
    for (int k = 0; k < 4; ++k) t -= dHtRi[r8*4 + k] * (double)H[k*8 + c8];
    // lane (i=r8, k=c8) owns Mx/Mp[i][k] -> transposed slots [k*8+i]
    fmats[       c8*8 + r8] = (float)(((r8 == c8) ? 1.0 : 0.0) + g * t);
    fmats[ 64 +  c8*8 + r8] = (float)(g * sp);
    fmats[128 +  c8*8 + r8] = (float)(g * dB2[r8*8 + c8]);
    if (lane < 32) {
      int i = lane >> 2, j = lane & 3;   // owns HtRi[i][j]
      fmats[192 + j*8 + i] = (float)(g * dHtRi[i*4 + j]);
    }
  }
  __syncthreads();

  // ---- hoist coefficients into VGPRs (broadcast LDS reads, once) ----
  float cmv[64], pmv[64], fuv[56];
  #pragma unroll
  for (int t = 0; t < 64; ++t) cmv[t] = fmats[t];
  #pragma unroll
  for (int t = 0; t < 64; ++t) pmv[t] = fmats[64 + t];
  #pragma unroll
  for (int t = 0; t < 56; ++t) fuv[t] = fmats[128 + t];

  if (b < 6) {
    // ---- weight recurrence: W'_s = Cm*W_s + P*W_{s+1} + Fu*W_{s-1} ----
    const int sub = lane / 23;
    const int s   = lane % 23;          // slot; 0 and 22 are guards
    const int c   = 2*b + sub;          // source column 0..11
    const bool act   = (sub < 2);
    const bool guard = (s == 0) || (s == 22) || !act;
    float x[8];
    #pragma unroll
    for (int r = 0; r < 8; ++r) x[r] = 0.0f;
    if (act && c < 8 && s == DHALF + 1) x[c] = 1.0f;   // W_0 = I
    float seed[8];
    {
      const int gk = (c >= 8 && c < 12) ? (c - 8) : 0;
      const bool inj = act && (c >= 8) && (c < 12) && (s == DHALF + 1);
      #pragma unroll
      for (int i = 0; i < 8; ++i) seed[i] = inj ? fmats[192 + gk*8 + i] : 0.0f;
    }
    const int sl = (lane == 0)  ? 0  : lane - 1;
    const int sr = (lane >= 63) ? 63 : lane + 1;
    #pragma unroll 1
    for (int it = 0; it < NITER; ++it) {
      float xl[8], xr[8];
      #pragma unroll
      for (int r = 0; r < 8; ++r) { xl[r] = __shfl(x[r], sl); xr[r] = __shfl(x[r], sr); }
      float nx[8];
      #pragma unroll
      for (int i = 0; i < 8; ++i) nx[i] = seed[i];
      #pragma unroll
      for (int k = 0; k < 8; ++k) {
        #pragma unroll
        for (int i = 0; i < 8; ++i) {
          nx[i] = fmaf(cmv[k*8 + i], x[k],  nx[i]);      // Cm
          nx[i] = fmaf(pmv[k*8 + i], xr[k], nx[i]);      // P  * W_{s+1}
          if (k < 7)
            nx[i] = fmaf(fuv[k*8 + i], xl[k], nx[i]);    // Fu * W_{s-1}
        }
      }
      #pragma unroll
      for (int r = 0; r < 8; ++r) x[r] = guard ? 0.0f : nx[r];
    }
    if (act && s >= 1 && s <= 21) {
      #pragma unroll
      for (int i = 0; i < 8; ++i) wout[((s - 1)*12 + c)*8 + i] = x[i];
    }
    return;
  }

  // ---- edge strips: exact iteration on 64 columns, halo via shuffles ----
  const bool left = (b == 6);
  const int col = left ? lane : (TLEN - EWIN + lane);
  float x[8], gy[8];
  #pragma unroll
  for (int r = 0; r < 8; ++r) x[r] = xs[r*TLEN + col];
  {
    float yv[4];
    #pragma unroll
    for (int r = 0; r < 4; ++r) yv[r] = ys[r*TLEN + col];
    #pragma unroll
    for (int i = 0; i < 8; ++i) {
      float a =      fmats[192 +      i] * yv[0];
      a = fmaf(fmats[192 +  8 + i], yv[1], a);
      a = fmaf(fmats[192 + 16 + i], yv[2], a);
      a = fmaf(fmats[192 + 24 + i], yv[3], a);
      gy[i] = a;
    }
  }
  const int sl = (lane > 0)  ? lane - 1 : 0;    // clamp: col 0 replicates (x_past)
  const int sr = (lane < 63) ? lane + 1 : 63;   // clamp: col T-1 replicates (x_fut)
  #pragma unroll 1
  for (int it = 0; it < NITER; ++it) {
    float xl[8], xr[8];
    #pragma unroll
    for (int r = 0; r < 8; ++r) { xl[r] = __shfl(x[r], sl); xr[r] = __shfl(x[r], sr); }
    float nx[8];
    #pragma unroll
    for (int i = 0; i < 8; ++i) nx[i] = gy[i];
    #pragma unroll
    for (int k = 0; k < 8; ++k) {
      #pragma unroll
      for (int i = 0; i < 8; ++i) {
        nx[i] = fmaf(cmv[k*8 + i], x[k],  nx[i]);        // Cm
        nx[i] = fmaf(pmv[k*8 + i], xl[k], nx[i]);        // P  * x_{t-1}
        if (k < 7)
          nx[i] = fmaf(fuv[k*8 + i], xr[k], nx[i]);      // Fu * x_{t+1}
      }
    }
    #pragma unroll
    for (int r = 0; r < 8; ++r) x[r] = nx[r];
  }
  if (left) {
    if (lane < STRIP)
      #pragma unroll
      for (int r = 0; r < 8; ++r) out[r*TLEN + col] = x[r];
  } else {
    if (lane >= EWIN - STRIP)
      #pragma unroll
      for (int r = 0; r < 8; ++r) out[r*TLEN + col] = x[r];
  }
}

// ============ K2: interior band convolution ============
__global__ __launch_bounds__(CT) void kgm_conv(
    const float* __restrict__ xs, const float* __restrict__ ys,
    const float* __restrict__ wq, float* __restrict__ out)
{
  __shared__ __align__(16) float buf[CWIN * 12];   // [col][12], 48B stride
  const int tid = threadIdx.x;
  const int c0  = STRIP + blockIdx.x * CCOLS;
  for (int k = 0; k < 12; ++k) {
    const float* src = (k < 8) ? (xs + k*TLEN) : (ys + (k-8)*TLEN);
    for (int c = tid; c < CWIN; c += CT) {
      int g = c0 - DHALF + c;
      if (g > TLEN - 1) g = TLEN - 1;
      buf[c*12 + k] = src[g];
    }
  }
  __syncthreads();

  const float* base = buf + (2*tid)*12;
  float a0[8] = {0,0,0,0,0,0,0,0};
  float a1[8] = {0,0,0,0,0,0,0,0};
  float A[12], B[12];
  {
    float4 u = *(const float4*)(base);
    float4 v = *(const float4*)(base + 4);
    float4 w = *(const float4*)(base + 8);
    A[0]=u.x;A[1]=u.y;A[2]=u.z;A[3]=u.w;A[4]=v.x;A[5]=v.y;A[6]=v.z;A[7]=v.w;A[8]=w.x;A[9]=w.y;A[10]=w.z;A[11]=w.w;
  }
  #define LOADCOL(dst, j1) { \
    const float* p_ = base + (j1)*12; \
    float4 u = *(const float4*)(p_); \
    float4 v = *(const float4*)(p_ + 4); \
    float4 w = *(const float4*)(p_ + 8); \
    dst[0]=u.x;dst[1]=u.y;dst[2]=u.z;dst[3]=u.w;dst[4]=v.x;dst[5]=v.y;dst[6]=v.z;dst[7]=v.w;dst[8]=w.x;dst[9]=w.y;dst[10]=w.z;dst[11]=w.w; }
  #define FMABLK(wd, c0v, c1v) { \
    _Pragma("unroll") \
    for (int k = 0; k < 12; ++k) { \
      _Pragma("unroll") \
      for (int i = 0; i < 8; ++i) { \
        float wk = (wd)[k*8 + i]; \
        a0[i] = fmaf(wk, (c0v)[k], a0[i]); \
        a1[i] = fmaf(wk, (c1v)[k], a1[i]); \
      } } }

  #pragma unroll 1
  for (int j = 0; j + 2 <= NOFF; j += 2) {
    LOADCOL(B, j + 1);
    FMABLK(wq + j*96, A, B);
    LOADCOL(A, j + 2);
    FMABLK(wq + (j+1)*96, B, A);
  }
  LOADCOL(B, NOFF);
  FMABLK(wq + (NOFF-1)*96, A, B);
  #undef LOADCOL
  #undef FMABLK

  const int col = c0 + 2*tid;
  if (col < TLEN - STRIP) {
    #pragma unroll
    for (int i = 0; i < 8; ++i) out[i*TLEN + col] = a0[i];
  }
  if (col + 1 < TLEN - STRIP) {
    #pragma unroll
    for (int i = 0; i < 8; ++i) out[i*TLEN + col + 1] = a1[i];
  }
}

extern "C" void kernel_launch(void* const* d_in, const int* in_sizes, int n_in,
                              void* d_out, int out_size, void* d_ws, size_t ws_size,
                              hipStream_t stream)
{
  (void)in_sizes; (void)n_in; (void)out_size; (void)ws_size;
  const float* xs = (const float*)d_in[0];
  const float* ys = (const float*)d_in[1];
  const float* F  = (const float*)d_in[2];
  const float* H  = (const float*)d_in[3];
  const float* Q  = (const float*)d_in[4];
  const float* R  = (const float*)d_in[5];
  const float* ga = (const float*)d_in[6];
  float* ws  = (float*)d_ws;     // [0, 2016): band weights
  float* out = (float*)d_out;
  band_and_edges<<<8, 64, 0, stream>>>(xs, ys, F, H, Q, R, ga, ws, out);
  kgm_conv<<<NCONV, CT, 0, stream>>>(xs, ys, ws, out);
}